// Round 10
// baseline (84.609 us; speedup 1.0000x reference)
//
#include <hip/hip_runtime.h>

#define LL 8192

typedef __attribute__((ext_vector_type(8))) short bf16x8;
typedef __attribute__((ext_vector_type(4))) float f32x4;

union U4 { uint4 u; bf16x8 v; };

__device__ __forceinline__ float4 ld4(const float* p) {
    return *reinterpret_cast<const float4*>(p);
}
__device__ __forceinline__ unsigned short f2bf(float f) {
    union { float f; unsigned u; } v; v.f = f;
    unsigned r = v.u + 0x7fffu + ((v.u >> 16) & 1u);
    return (unsigned short)(r >> 16);
}
__device__ __forceinline__ unsigned cvt_pk_bf16(float lo, float hi) {
    unsigned r;
    asm("v_cvt_pk_bf16_f32 %0, %1, %2" : "=v"(r) : "v"(lo), "v"(hi));
    return r;
}

// ---------------------------------------------------------------------------
// kernA1: Gram of c0 over a 1024-position chunk via MFMA (A-frag == B-frag).
// Register-direct c0: no x staging in LDS; 16 ds_write_b64/thread total.
// grid = 256*8, block = 256
// ---------------------------------------------------------------------------
__global__ __launch_bounds__(256) void kernA1(
    const float* __restrict__ x, const float* __restrict__ wc1,
    const float* __restrict__ g1, const float* __restrict__ bt1,
    const float* __restrict__ m1, const float* __restrict__ v1,
    float* __restrict__ partial)
{
    __shared__ __align__(16) unsigned short c0f[16384];   // 32 KB frag-slot layout
    __shared__ float gsum[1024];                          // 4 KB

    const int blk = blockIdx.x;
    const int b = blk >> 3, chunk = blk & 7;
    const int t = threadIdx.x;
    const int w = t >> 6, l = t & 63;
    const float* xb = x + (size_t)b * 4 * LL;
    const int p0 = chunk << 10;

    // thread t owns chunk-local positions p = 4t .. 4t+3, all 4 channels
    const float4 x0 = ld4(&xb[0 * LL + p0 + 4 * t]);
    const float4 x1 = ld4(&xb[1 * LL + p0 + 4 * t]);
    const float4 x2 = ld4(&xb[2 * LL + p0 + 4 * t]);
    const float4 x3 = ld4(&xb[3 * LL + p0 + 4 * t]);

    // frag-slot layout: slot = (p>>5)*64 + ((p>>3)&3)*16 + u, elem = p&7
    const int p = 4 * t;
    unsigned short* dst =
        &c0f[(((p >> 5) << 6) + (((p >> 3) & 3) << 4)) * 8 + (p & 7)];
    #pragma unroll
    for (int u = 0; u < 16; ++u) {
        float inv = g1[u] * rsqrtf(v1[u] + 1e-5f);
        float w0 = wc1[u * 4 + 0] * inv, w1 = wc1[u * 4 + 1] * inv;
        float w2 = wc1[u * 4 + 2] * inv, w3 = wc1[u * 4 + 3] * inv;
        float bu = bt1[u] - m1[u] * inv;
        float ca = fmaxf(bu + w0 * x0.x + w1 * x1.x + w2 * x2.x + w3 * x3.x, 0.f);
        float cb = fmaxf(bu + w0 * x0.y + w1 * x1.y + w2 * x2.y + w3 * x3.y, 0.f);
        float cc = fmaxf(bu + w0 * x0.z + w1 * x1.z + w2 * x2.z + w3 * x3.z, 0.f);
        float cd = fmaxf(bu + w0 * x0.w + w1 * x1.w + w2 * x2.w + w3 * x3.w, 0.f);
        uint2 pk;
        pk.x = cvt_pk_bf16(ca, cb);
        pk.y = cvt_pk_bf16(cc, cd);
        *reinterpret_cast<uint2*>(dst + u * 8) = pk;
    }
    __syncthreads();

    // Gram: wave w covers positions 256w..256w+255 -> 8 MFMAs, frag = one b128
    f32x4 acc = {0.f, 0.f, 0.f, 0.f};
    #pragma unroll
    for (int m = 0; m < 8; ++m) {
        int slot = (w * 8 + m) * 64 + l;
        bf16x8 fr = *reinterpret_cast<const bf16x8*>(&c0f[slot * 8]);
        acc = __builtin_amdgcn_mfma_f32_16x16x32_bf16(fr, fr, acc, 0, 0, 0);
    }

    {
        int col = l & 15, rg = l >> 4;
        #pragma unroll
        for (int i = 0; i < 4; ++i)
            gsum[w * 256 + (rg * 4 + i) * 16 + col] = acc[i];
    }
    __syncthreads();
    partial[(size_t)(b * 8 + chunk) * 256 + t] =
        gsum[t] + gsum[256 + t] + gsum[512 + t] + gsum[768 + t];
}

// ---------------------------------------------------------------------------
// kernA2: reduce partials -> softmax -> M -> Mp; block 0 also packs weights.
// grid 256
// ---------------------------------------------------------------------------
__global__ __launch_bounds__(256) void kernA2(
    const float* __restrict__ partial, const float* __restrict__ beta_cam,
    const float* __restrict__ wc2, const float* __restrict__ g2,
    const float* __restrict__ bt2, const float* __restrict__ m2,
    const float* __restrict__ v2,
    const float* __restrict__ w00, const float* __restrict__ w01,
    const float* __restrict__ w02,
    const float* __restrict__ wc1, const float* __restrict__ g1,
    const float* __restrict__ bt1, const float* __restrict__ m1,
    const float* __restrict__ v1,
    unsigned short* __restrict__ Mp,
    unsigned short* __restrict__ wA0, unsigned short* __restrict__ wA1,
    unsigned short* __restrict__ wc0A)
{
    __shared__ float gram[16][16];
    __shared__ float attn[16][16];
    __shared__ float Msh[16][16];
    const int b = blockIdx.x, t = threadIdx.x;

    if (b == 0) {   // pack conv weights into MFMA fragment order
        // ---- wA0: fea0 dual-position packing (6 chunks) ----
        for (int i = t; i < 384; i += 256) {
            const int c = i >> 6, li = i & 63;
            const int row = li & 15, g = li >> 4;
            #pragma unroll
            for (int j = 0; j < 8; ++j) {
                int ch = j & 3;
                int T = 8 * c + g + ((j >= 4) ? 4 : 0);
                float v = 0.f;
                if (row < 8) {
                    if (T < 32) v = w00[(row * 4 + ch) * 32 + T];
                } else {
                    int tt = T - 16;
                    if (tt >= 0) v = w00[((row - 8) * 4 + ch) * 32 + tt];
                }
                wA0[(c * 64 + li) * 8 + j] = f2bf(v);
            }
        }
        // ---- wA1: fusion dense packing (8 chunks, q = 4c+g) ----
        for (int i = t; i < 512; i += 256) {
            const int c = i >> 6, li = i & 63;
            const int row = li & 15, g = li >> 4;
            int q = 4 * c + g;
            #pragma unroll
            for (int j = 0; j < 8; ++j) {
                float v = 0.f;
                if (row < 8) {
                    if (q >= 7 && q <= 22) v = w01[(row * 8 + j) * 16 + (q - 7)];
                } else {
                    if (!(q & 1)) v = w02[((row - 8) * 8 + j) * 16 + (q >> 1)];
                }
                wA1[(c * 64 + li) * 8 + j] = f2bf(v);
            }
        }
        // ---- wc0A: c0 1x1-conv A-frag, bias folded at k=4 ----
        if (t < 64) {
            int u = t & 15, gg = t >> 4;
            float inv = g1[u] * rsqrtf(v1[u] + 1e-5f);
            #pragma unroll
            for (int j = 0; j < 8; ++j) {
                float v = 0.f;
                if (gg == 0) {
                    if (j < 4) v = wc1[u * 4 + j] * inv;
                    else if (j == 4) v = bt1[u] - m1[u] * inv;
                }
                wc0A[t * 8 + j] = f2bf(v);
            }
        }
    }

    const float* P = partial + (size_t)b * 2048;
    float s = 0.f;
    #pragma unroll
    for (int k = 0; k < 8; ++k) s += P[k * 256 + t];
    gram[t >> 4][t & 15] = s;
    __syncthreads();
    {
        const float beta = beta_cam[0];
        int d = t & 15;
        float gv = gram[t >> 4][d];
        float rm = gv;
        #pragma unroll
        for (int m = 1; m < 16; m <<= 1) rm = fmaxf(rm, __shfl_xor(rm, m, 64));
        float a = rm - gv;
        float am = a;
        #pragma unroll
        for (int m = 1; m < 16; m <<= 1) am = fmaxf(am, __shfl_xor(am, m, 64));
        float e = __expf(a - am);
        float ssum = e;
        #pragma unroll
        for (int m = 1; m < 16; m <<= 1) ssum += __shfl_xor(ssum, m, 64);
        attn[t >> 4][d] = beta * e / ssum;
    }
    __syncthreads();
    {
        int o = t >> 4, u = t & 15;
        float inv2 = g2[o] * rsqrtf(v2[o] + 1e-5f);
        float sm = wc2[o * 16 + u];
        #pragma unroll
        for (int d = 0; d < 16; ++d) sm += wc2[o * 16 + d] * attn[d][u];
        Msh[o][u] = sm * inv2;
    }
    __syncthreads();
    for (int idx = t; idx < 512; idx += 256) {
        int li = idx >> 3, j = idx & 7;
        int k = 8 * (li >> 4) + j, o = li & 15;
        float v = (k < 16) ? Msh[o][k] : 0.f;
        Mp[(size_t)b * 512 + idx] = f2bf(v);
    }
}

// ---------------------------------------------------------------------------
// kernB: MFMA conv pipeline (R8 phase-2 form) at 5 blocks/CU + nontemporal
// output stores. grid 256*16, block 256 (4 waves), T=512 positions per block.
// ---------------------------------------------------------------------------
__global__ __launch_bounds__(256, 5) void kernB(
    const float* __restrict__ x,
    const float* __restrict__ b00, const float* __restrict__ b01,
    const float* __restrict__ b02,
    const float* __restrict__ g2, const float* __restrict__ bt2,
    const float* __restrict__ m2, const float* __restrict__ v2,
    const unsigned short* __restrict__ wA0, const unsigned short* __restrict__ wA1,
    const unsigned short* __restrict__ wc0A,
    const unsigned short* __restrict__ Mp, float* __restrict__ out)
{
    // xT row i: elems 0..3 = x[0..3][p0-32+i], elems 4..7 = x[0..3][p0-32+i+4]
    __shared__ __align__(16) unsigned short xT[608][8];
    __shared__ __align__(16) unsigned short f0T[576][8];  // slot s <-> j = p0-16+s

    const int blk = blockIdx.x;
    const int b  = blk >> 4;
    const int p0 = (blk & 15) << 9;
    const int t  = threadIdx.x;
    const int w  = t >> 6, l = t & 63;
    const int lane15 = l & 15, g = l >> 4;
    const float* xb = x + (size_t)b * 4 * LL;
    const bool intr = (p0 != 0) && (p0 != 15 * 512);

    // ---- stage xT: one load per row -> row i lower + row i-4 upper ----
    if (intr) {
        for (int i = t; i < 608; i += 256) {
            int xp = p0 - 32 + i;
            float v0  = xb[0 * LL + xp];
            float v1_ = xb[1 * LL + xp];
            float v2_ = xb[2 * LL + xp];
            float v3_ = xb[3 * LL + xp];
            uint2 r;
            r.x = cvt_pk_bf16(v0, v1_);
            r.y = cvt_pk_bf16(v2_, v3_);
            *reinterpret_cast<uint2*>(&xT[i][0]) = r;
            if (i >= 4)
                *reinterpret_cast<uint2*>(&xT[i - 4][4]) = r;
        }
    } else {
        for (int i = t; i < 608; i += 256) {
            int xp = p0 - 32 + i;
            bool ok = (unsigned)xp < 8192u;
            float v0  = ok ? xb[0 * LL + xp] : 0.f;
            float v1_ = ok ? xb[1 * LL + xp] : 0.f;
            float v2_ = ok ? xb[2 * LL + xp] : 0.f;
            float v3_ = ok ? xb[3 * LL + xp] : 0.f;
            uint2 r;
            r.x = cvt_pk_bf16(v0, v1_);
            r.y = cvt_pk_bf16(v2_, v3_);
            *reinterpret_cast<uint2*>(&xT[i][0]) = r;
            if (i >= 4)
                *reinterpret_cast<uint2*>(&xT[i - 4][4]) = r;
        }
    }

    // preload phase-1 weights + bias
    bf16x8 a0[6];
    #pragma unroll
    for (int c = 0; c < 6; ++c)
        a0[c] = reinterpret_cast<const bf16x8*>(wA0)[c * 64 + l];
    float b00c[4];
    #pragma unroll
    for (int i = 0; i < 4; ++i) b00c[i] = b00[(4 * g + i) & 7];

    __syncthreads();

    // ---- phase 1: fea0 via dual-packed MFMA, 32 positions per 6-MFMA group ----
    {
        const int ngrp = (w < 2) ? 5 : 4;
        const int grp0 = (w < 2) ? 5 * w : 10 + 4 * (w - 2);
        const unsigned short* xrow = &xT[32 * grp0 + lane15 + g][0];
        const int s_base = 32 * grp0 + lane15 + ((g >= 2) ? 16 : 0);
        unsigned short* wp = &f0T[s_base][4 * (g & 1)];
        bf16x8 bb[6];
        #pragma unroll
        for (int c = 0; c < 6; ++c)
            bb[c] = *reinterpret_cast<const bf16x8*>(xrow + 64 * c);
        #pragma unroll
        for (int it = 0; it < 5; ++it) {
            if (it < ngrp) {
                f32x4 d = {b00c[0], b00c[1], b00c[2], b00c[3]};
                #pragma unroll
                for (int c = 0; c < 6; ++c)
                    d = __builtin_amdgcn_mfma_f32_16x16x32_bf16(a0[c], bb[c], d, 0, 0, 0);
                float e0 = d[0], e1 = d[1], e2 = d[2], e3 = d[3];
                if (!intr) {
                    int j = p0 - 16 + s_base + 32 * it;
                    bool ok = (unsigned)j <= 8192u;
                    e0 = ok ? e0 : 0.f;  e1 = ok ? e1 : 0.f;
                    e2 = ok ? e2 : 0.f;  e3 = ok ? e3 : 0.f;
                }
                uint2 wv;
                wv.x = cvt_pk_bf16(e0, e1);
                wv.y = cvt_pk_bf16(e2, e3);
                *reinterpret_cast<uint2*>(wp + 256 * it) = wv;
                if (it + 1 < ngrp) {       // slide window: chunks 4,5 -> 0,1
                    bb[0] = bb[4]; bb[1] = bb[5];
                    #pragma unroll
                    for (int c = 2; c < 6; ++c)
                        bb[c] = *reinterpret_cast<const bf16x8*>(
                            xrow + 32 * 8 * (it + 1) + 64 * c);
                }
            }
        }
    }

    // preload phase-2 constants
    bf16x8 a1[8];
    #pragma unroll
    for (int c = 0; c < 8; ++c)
        a1[c] = reinterpret_cast<const bf16x8*>(wA1)[c * 64 + l];
    bf16x8 mfrag  = reinterpret_cast<const bf16x8*>(Mp)[b * 64 + l];
    bf16x8 wc0Af  = reinterpret_cast<const bf16x8*>(wc0A)[l];
    float cb1[4], bf2v[4];
    #pragma unroll
    for (int i = 0; i < 4; ++i) {
        int o = 4 * g + i;
        cb1[i] = (o < 8) ? b01[o] : b02[o - 8];
        float inv2 = g2[o] * rsqrtf(v2[o] + 1e-5f);
        bf2v[i] = bt2[o] - m2[o] * inv2;
    }
    const unsigned mask1 = (g == 0) ? 0x3f80u : 0u;
    const bool g0 = (g == 0);
    // shuffle sources for c0 D->B-frag redistribution
    const int s0 = (lane15 + 32 * g) & 63;
    const int s1 = (s0 + 16) & 63;

    __syncthreads();

    // ---- phase 2: fusion (dense slide) + c0-MFMA + c2-MFMA + store ----
    {
        const int gi0 = 8 * w;
        const unsigned short* frow = &f0T[16 * gi0 + lane15 + g + 2][0];
        const unsigned short* xrow2 = &xT[16 * gi0 + lane15 + 32][0];
        const size_t obase = (size_t)b * 16 * LL + p0 + 16 * gi0 + lane15;
        float* o0 = out + obase + (size_t)(4 * g + 0) * LL;
        float* o1 = out + obase + (size_t)(4 * g + 1) * LL;
        float* o2 = out + obase + (size_t)(4 * g + 2) * LL;
        float* o3 = out + obase + (size_t)(4 * g + 3) * LL;
        const f32x4 zc = {0.f, 0.f, 0.f, 0.f};

        bf16x8 bb[8];
        #pragma unroll
        for (int c = 0; c < 8; ++c)
            bb[c] = *reinterpret_cast<const bf16x8*>(frow + 32 * c);
        #pragma unroll
        for (int it = 0; it < 8; ++it) {
            f32x4 dF = {cb1[0], cb1[1], cb1[2], cb1[3]};
            #pragma unroll
            for (int c = 0; c < 8; ++c)
                dF = __builtin_amdgcn_mfma_f32_16x16x32_bf16(a1[c], bb[c], dF, 0, 0, 0);

            // c0_pre = MFMA(wc0A, [x;1]) : D rows u=4G+i, cols = position
            uint2 xr = *reinterpret_cast<const uint2*>(xrow2 + 128 * it);
            U4 xu;
            xu.u.x = g0 ? xr.x : 0u;
            xu.u.y = g0 ? xr.y : 0u;
            xu.u.z = mask1;
            xu.u.w = 0u;
            f32x4 dP = __builtin_amdgcn_mfma_f32_16x16x32_bf16(wc0Af, xu.v, zc, 0, 0, 0);
            unsigned pk0 = cvt_pk_bf16(fmaxf(dP[0], 0.f), fmaxf(dP[1], 0.f));
            unsigned pk1 = cvt_pk_bf16(fmaxf(dP[2], 0.f), fmaxf(dP[3], 0.f));
            U4 uu;
            uu.u.x = __shfl(pk0, s0, 64);
            uu.u.y = __shfl(pk1, s0, 64);
            uu.u.z = __shfl(pk0, s1, 64);
            uu.u.w = __shfl(pk1, s1, 64);
            f32x4 dC = {bf2v[0], bf2v[1], bf2v[2], bf2v[3]};
            dC = __builtin_amdgcn_mfma_f32_16x16x32_bf16(mfrag, uu.v, dC, 0, 0, 0);

            float c20 = fmaxf(dC[0], 0.f), c21 = fmaxf(dC[1], 0.f);
            float c22 = fmaxf(dC[2], 0.f), c23 = fmaxf(dC[3], 0.f);
            float r0 = dF[0] + c20, r1 = dF[1] + c21;
            float r2 = dF[2] + c22, r3 = dF[3] + c23;
            if (!intr) {
                int p = p0 + 16 * (gi0 + it) + lane15;
                if (((p < 1) | (p > LL - 3)) && g >= 2) {
                    r0 = c20; r1 = c21; r2 = c22; r3 = c23;
                }
            }
            __builtin_nontemporal_store(r0, o0 + 16 * it);
            __builtin_nontemporal_store(r1, o1 + 16 * it);
            __builtin_nontemporal_store(r2, o2 + 16 * it);
            __builtin_nontemporal_store(r3, o3 + 16 * it);

            if (it < 7) {       // slide: chunks 4..7 -> 0..3, read 4 new
                bb[0] = bb[4]; bb[1] = bb[5]; bb[2] = bb[6]; bb[3] = bb[7];
                #pragma unroll
                for (int c = 4; c < 8; ++c)
                    bb[c] = *reinterpret_cast<const bf16x8*>(
                        frow + 16 * 8 * (it + 1) + 32 * c);
            }
        }
    }
}

extern "C" void kernel_launch(void* const* d_in, const int* in_sizes, int n_in,
                              void* d_out, int out_size, void* d_ws, size_t ws_size,
                              hipStream_t stream)
{
    const float* x    = (const float*)d_in[0];
    const float* w00  = (const float*)d_in[1];
    const float* b00  = (const float*)d_in[2];
    const float* w01  = (const float*)d_in[3];
    const float* b01  = (const float*)d_in[4];
    const float* w02  = (const float*)d_in[5];
    const float* b02  = (const float*)d_in[6];
    const float* wc1  = (const float*)d_in[7];
    const float* g1   = (const float*)d_in[8];
    const float* bt1  = (const float*)d_in[9];
    const float* m1   = (const float*)d_in[10];
    const float* v1   = (const float*)d_in[11];
    const float* beta = (const float*)d_in[12];
    const float* wc2  = (const float*)d_in[13];
    const float* g2   = (const float*)d_in[14];
    const float* bt2  = (const float*)d_in[15];
    const float* m2   = (const float*)d_in[16];
    const float* v2   = (const float*)d_in[17];

    char* wsb = (char*)d_ws;
    float* partialp       = (float*)wsb;                       // 2,097,152 B
    unsigned short* Mpp   = (unsigned short*)(wsb + 2097152);  // 262,144 B
    unsigned short* wA0p  = (unsigned short*)(wsb + 2359296);  // 6,144 B
    unsigned short* wA1p  = (unsigned short*)(wsb + 2365440);  // 8,192 B
    unsigned short* wc0Ap = (unsigned short*)(wsb + 2373632);  // 1,024 B
    float* o = (float*)d_out;

    hipLaunchKernelGGL(kernA1, dim3(2048), dim3(256), 0, stream,
        x, wc1, g1, bt1, m1, v1, partialp);
    hipLaunchKernelGGL(kernA2, dim3(256), dim3(256), 0, stream,
        partialp, beta, wc2, g2, bt2, m2, v2, w00, w01, w02,
        wc1, g1, bt1, m1, v1, Mpp, wA0p, wA1p, wc0Ap);
    hipLaunchKernelGGL(kernB, dim3(4096), dim3(256), 0, stream,
        x, b00, b01, b02, g2, bt2, m2, v2,
        wA0p, wA1p, wc0Ap, Mpp, o);
}

// Round 11
// 67.281 us; speedup vs baseline: 1.2575x; 1.2575x over previous
//
#include <hip/hip_runtime.h>

#define LL 8192

typedef __attribute__((ext_vector_type(8))) short bf16x8;
typedef __attribute__((ext_vector_type(4))) float f32x4;

union U4 { uint4 u; bf16x8 v; };

__device__ __forceinline__ float4 ld4(const float* p) {
    return *reinterpret_cast<const float4*>(p);
}
__device__ __forceinline__ unsigned short f2bf(float f) {
    union { float f; unsigned u; } v; v.f = f;
    unsigned r = v.u + 0x7fffu + ((v.u >> 16) & 1u);
    return (unsigned short)(r >> 16);
}
__device__ __forceinline__ unsigned cvt_pk_bf16(float lo, float hi) {
    unsigned r;
    asm("v_cvt_pk_bf16_f32 %0, %1, %2" : "=v"(r) : "v"(lo), "v"(hi));
    return r;
}

// ---------------------------------------------------------------------------
// kernA1: Gram of c0 over a 1024-position chunk via MFMA (A-frag == B-frag).
// grid = 256*8, block = 256
// ---------------------------------------------------------------------------
__global__ __launch_bounds__(256) void kernA1(
    const float* __restrict__ x, const float* __restrict__ wc1,
    const float* __restrict__ g1, const float* __restrict__ bt1,
    const float* __restrict__ m1, const float* __restrict__ v1,
    float* __restrict__ partial)
{
    __shared__ __align__(16) unsigned short c0f[16384];   // 32 KB frag-slot layout
    __shared__ float gsum[1024];                          // 4 KB

    const int blk = blockIdx.x;
    const int b = blk >> 3, chunk = blk & 7;
    const int t = threadIdx.x;
    const int w = t >> 6, l = t & 63;
    const float* xb = x + (size_t)b * 4 * LL;
    const int p0 = chunk << 10;

    const float4 x0 = ld4(&xb[0 * LL + p0 + 4 * t]);
    const float4 x1 = ld4(&xb[1 * LL + p0 + 4 * t]);
    const float4 x2 = ld4(&xb[2 * LL + p0 + 4 * t]);
    const float4 x3 = ld4(&xb[3 * LL + p0 + 4 * t]);

    const int p = 4 * t;
    unsigned short* dst =
        &c0f[(((p >> 5) << 6) + (((p >> 3) & 3) << 4)) * 8 + (p & 7)];
    #pragma unroll
    for (int u = 0; u < 16; ++u) {
        float inv = g1[u] * rsqrtf(v1[u] + 1e-5f);
        float w0 = wc1[u * 4 + 0] * inv, w1 = wc1[u * 4 + 1] * inv;
        float w2 = wc1[u * 4 + 2] * inv, w3 = wc1[u * 4 + 3] * inv;
        float bu = bt1[u] - m1[u] * inv;
        float ca = fmaxf(bu + w0 * x0.x + w1 * x1.x + w2 * x2.x + w3 * x3.x, 0.f);
        float cb = fmaxf(bu + w0 * x0.y + w1 * x1.y + w2 * x2.y + w3 * x3.y, 0.f);
        float cc = fmaxf(bu + w0 * x0.z + w1 * x1.z + w2 * x2.z + w3 * x3.z, 0.f);
        float cd = fmaxf(bu + w0 * x0.w + w1 * x1.w + w2 * x2.w + w3 * x3.w, 0.f);
        uint2 pk;
        pk.x = cvt_pk_bf16(ca, cb);
        pk.y = cvt_pk_bf16(cc, cd);
        *reinterpret_cast<uint2*>(dst + u * 8) = pk;
    }
    __syncthreads();

    f32x4 acc = {0.f, 0.f, 0.f, 0.f};
    #pragma unroll
    for (int m = 0; m < 8; ++m) {
        int slot = (w * 8 + m) * 64 + l;
        bf16x8 fr = *reinterpret_cast<const bf16x8*>(&c0f[slot * 8]);
        acc = __builtin_amdgcn_mfma_f32_16x16x32_bf16(fr, fr, acc, 0, 0, 0);
    }

    {
        int col = l & 15, rg = l >> 4;
        #pragma unroll
        for (int i = 0; i < 4; ++i)
            gsum[w * 256 + (rg * 4 + i) * 16 + col] = acc[i];
    }
    __syncthreads();
    partial[(size_t)(b * 8 + chunk) * 256 + t] =
        gsum[t] + gsum[256 + t] + gsum[512 + t] + gsum[768 + t];
}

// ---------------------------------------------------------------------------
// kernA2: reduce partials -> softmax -> M -> Mp; block 0 also packs weights.
// grid 256
// ---------------------------------------------------------------------------
__global__ __launch_bounds__(256) void kernA2(
    const float* __restrict__ partial, const float* __restrict__ beta_cam,
    const float* __restrict__ wc2, const float* __restrict__ g2,
    const float* __restrict__ bt2, const float* __restrict__ m2,
    const float* __restrict__ v2,
    const float* __restrict__ w00, const float* __restrict__ w01,
    const float* __restrict__ w02,
    const float* __restrict__ wc1, const float* __restrict__ g1,
    const float* __restrict__ bt1, const float* __restrict__ m1,
    const float* __restrict__ v1,
    unsigned short* __restrict__ Mp,
    unsigned short* __restrict__ wA0, unsigned short* __restrict__ wA1,
    unsigned short* __restrict__ wc0A)
{
    __shared__ float gram[16][16];
    __shared__ float attn[16][16];
    __shared__ float Msh[16][16];
    const int b = blockIdx.x, t = threadIdx.x;

    if (b == 0) {   // pack conv weights into MFMA fragment order
        for (int i = t; i < 384; i += 256) {
            const int c = i >> 6, li = i & 63;
            const int row = li & 15, g = li >> 4;
            #pragma unroll
            for (int j = 0; j < 8; ++j) {
                int ch = j & 3;
                int T = 8 * c + g + ((j >= 4) ? 4 : 0);
                float v = 0.f;
                if (row < 8) {
                    if (T < 32) v = w00[(row * 4 + ch) * 32 + T];
                } else {
                    int tt = T - 16;
                    if (tt >= 0) v = w00[((row - 8) * 4 + ch) * 32 + tt];
                }
                wA0[(c * 64 + li) * 8 + j] = f2bf(v);
            }
        }
        for (int i = t; i < 512; i += 256) {
            const int c = i >> 6, li = i & 63;
            const int row = li & 15, g = li >> 4;
            int q = 4 * c + g;
            #pragma unroll
            for (int j = 0; j < 8; ++j) {
                float v = 0.f;
                if (row < 8) {
                    if (q >= 7 && q <= 22) v = w01[(row * 8 + j) * 16 + (q - 7)];
                } else {
                    if (!(q & 1)) v = w02[((row - 8) * 8 + j) * 16 + (q >> 1)];
                }
                wA1[(c * 64 + li) * 8 + j] = f2bf(v);
            }
        }
        if (t < 64) {
            int u = t & 15, gg = t >> 4;
            float inv = g1[u] * rsqrtf(v1[u] + 1e-5f);
            #pragma unroll
            for (int j = 0; j < 8; ++j) {
                float v = 0.f;
                if (gg == 0) {
                    if (j < 4) v = wc1[u * 4 + j] * inv;
                    else if (j == 4) v = bt1[u] - m1[u] * inv;
                }
                wc0A[t * 8 + j] = f2bf(v);
            }
        }
    }

    const float* P = partial + (size_t)b * 2048;
    float s = 0.f;
    #pragma unroll
    for (int k = 0; k < 8; ++k) s += P[k * 256 + t];
    gram[t >> 4][t & 15] = s;
    __syncthreads();
    {
        const float beta = beta_cam[0];
        int d = t & 15;
        float gv = gram[t >> 4][d];
        float rm = gv;
        #pragma unroll
        for (int m = 1; m < 16; m <<= 1) rm = fmaxf(rm, __shfl_xor(rm, m, 64));
        float a = rm - gv;
        float am = a;
        #pragma unroll
        for (int m = 1; m < 16; m <<= 1) am = fmaxf(am, __shfl_xor(am, m, 64));
        float e = __expf(a - am);
        float ssum = e;
        #pragma unroll
        for (int m = 1; m < 16; m <<= 1) ssum += __shfl_xor(ssum, m, 64);
        attn[t >> 4][d] = beta * e / ssum;
    }
    __syncthreads();
    {
        int o = t >> 4, u = t & 15;
        float inv2 = g2[o] * rsqrtf(v2[o] + 1e-5f);
        float sm = wc2[o * 16 + u];
        #pragma unroll
        for (int d = 0; d < 16; ++d) sm += wc2[o * 16 + d] * attn[d][u];
        Msh[o][u] = sm * inv2;
    }
    __syncthreads();
    for (int idx = t; idx < 512; idx += 256) {
        int li = idx >> 3, j = idx & 7;
        int k = 8 * (li >> 4) + j, o = li & 15;
        float v = (k < 16) ? Msh[o][k] : 0.f;
        Mp[(size_t)b * 512 + idx] = f2bf(v);
    }
}

// ---------------------------------------------------------------------------
// kernB: MFMA conv pipeline; c0 B-frags precomputed in phase 1 (per-wave,
// pre-redistributed in LDS) -> phase-2 chain = ds_read_b128 + c2-MFMA.
// grid 256*16, block 256 (4 waves), T=512 positions per block.
// ---------------------------------------------------------------------------
__global__ __launch_bounds__(256, 4) void kernB(
    const float* __restrict__ x,
    const float* __restrict__ b00, const float* __restrict__ b01,
    const float* __restrict__ b02,
    const float* __restrict__ g2, const float* __restrict__ bt2,
    const float* __restrict__ m2, const float* __restrict__ v2,
    const unsigned short* __restrict__ wA0, const unsigned short* __restrict__ wA1,
    const unsigned short* __restrict__ wc0A,
    const unsigned short* __restrict__ Mp, float* __restrict__ out)
{
    // xT row i: elems 0..3 = x[0..3][p0-32+i], elems 4..7 = x[0..3][p0-32+i+4]
    __shared__ __align__(16) unsigned short xT[608][8];
    __shared__ __align__(16) unsigned short f0T[576][8];  // slot s <-> j = p0-16+s
    __shared__ __align__(16) unsigned c0B[4096];          // [32 grp][16 pos][8 upair]

    const int blk = blockIdx.x;
    const int b  = blk >> 4;
    const int p0 = (blk & 15) << 9;
    const int t  = threadIdx.x;
    const int w  = t >> 6, l = t & 63;
    const int lane15 = l & 15, g = l >> 4;
    const float* xb = x + (size_t)b * 4 * LL;
    const bool intr = (p0 != 0) && (p0 != 15 * 512);

    // ---- stage xT: one load per row -> row i lower + row i-4 upper ----
    if (intr) {
        for (int i = t; i < 608; i += 256) {
            int xp = p0 - 32 + i;
            float v0  = xb[0 * LL + xp];
            float v1_ = xb[1 * LL + xp];
            float v2_ = xb[2 * LL + xp];
            float v3_ = xb[3 * LL + xp];
            uint2 r;
            r.x = cvt_pk_bf16(v0, v1_);
            r.y = cvt_pk_bf16(v2_, v3_);
            *reinterpret_cast<uint2*>(&xT[i][0]) = r;
            if (i >= 4)
                *reinterpret_cast<uint2*>(&xT[i - 4][4]) = r;
        }
    } else {
        for (int i = t; i < 608; i += 256) {
            int xp = p0 - 32 + i;
            bool ok = (unsigned)xp < 8192u;
            float v0  = ok ? xb[0 * LL + xp] : 0.f;
            float v1_ = ok ? xb[1 * LL + xp] : 0.f;
            float v2_ = ok ? xb[2 * LL + xp] : 0.f;
            float v3_ = ok ? xb[3 * LL + xp] : 0.f;
            uint2 r;
            r.x = cvt_pk_bf16(v0, v1_);
            r.y = cvt_pk_bf16(v2_, v3_);
            *reinterpret_cast<uint2*>(&xT[i][0]) = r;
            if (i >= 4)
                *reinterpret_cast<uint2*>(&xT[i - 4][4]) = r;
        }
    }

    // preload phase-1 weights + bias + c0 A-frag
    bf16x8 a0[6];
    #pragma unroll
    for (int c = 0; c < 6; ++c)
        a0[c] = reinterpret_cast<const bf16x8*>(wA0)[c * 64 + l];
    float b00c[4];
    #pragma unroll
    for (int i = 0; i < 4; ++i) b00c[i] = b00[(4 * g + i) & 7];
    bf16x8 wc0Af = reinterpret_cast<const bf16x8*>(wc0A)[l];
    const unsigned mask1 = (g == 0) ? 0x3f80u : 0u;
    const bool g0 = (g == 0);
    const f32x4 zc = {0.f, 0.f, 0.f, 0.f};

    __syncthreads();

    // ---- phase 1a: fea0 via dual-packed MFMA, 32 positions per 6-MFMA group ----
    {
        const int ngrp = (w < 2) ? 5 : 4;
        const int grp0 = (w < 2) ? 5 * w : 10 + 4 * (w - 2);
        const unsigned short* xrow = &xT[32 * grp0 + lane15 + g][0];
        const int s_base = 32 * grp0 + lane15 + ((g >= 2) ? 16 : 0);
        unsigned short* wp = &f0T[s_base][4 * (g & 1)];
        bf16x8 bb[6];
        #pragma unroll
        for (int c = 0; c < 6; ++c)
            bb[c] = *reinterpret_cast<const bf16x8*>(xrow + 64 * c);
        #pragma unroll
        for (int it = 0; it < 5; ++it) {
            if (it < ngrp) {
                f32x4 d = {b00c[0], b00c[1], b00c[2], b00c[3]};
                #pragma unroll
                for (int c = 0; c < 6; ++c)
                    d = __builtin_amdgcn_mfma_f32_16x16x32_bf16(a0[c], bb[c], d, 0, 0, 0);
                float e0 = d[0], e1 = d[1], e2 = d[2], e3 = d[3];
                if (!intr) {
                    int j = p0 - 16 + s_base + 32 * it;
                    bool ok = (unsigned)j <= 8192u;
                    e0 = ok ? e0 : 0.f;  e1 = ok ? e1 : 0.f;
                    e2 = ok ? e2 : 0.f;  e3 = ok ? e3 : 0.f;
                }
                uint2 wv;
                wv.x = cvt_pk_bf16(e0, e1);
                wv.y = cvt_pk_bf16(e2, e3);
                *reinterpret_cast<uint2*>(wp + 256 * it) = wv;
                if (it + 1 < ngrp) {       // slide window: chunks 4,5 -> 0,1
                    bb[0] = bb[4]; bb[1] = bb[5];
                    #pragma unroll
                    for (int c = 2; c < 6; ++c)
                        bb[c] = *reinterpret_cast<const bf16x8*>(
                            xrow + 32 * 8 * (it + 1) + 64 * c);
                }
            }
        }
    }

    // ---- phase 1b: c0 B-frags for this wave's phase-2 groups (8w..8w+7) ----
    // c0B[grp][pos][upair]: lane writes pk0@pair 2g, pk1@pair 2g+1 (b64);
    // phase-2 lane reads pairs 4g..4g+3 (one b128) = old post-shuffle uu.
    {
        const unsigned short* xrow2 = &xT[16 * (8 * w) + lane15 + 32][0];
        unsigned* c0w = &c0B[(8 * w) * 128 + lane15 * 8 + 2 * g];
        #pragma unroll
        for (int it = 0; it < 8; ++it) {
            uint2 xr;
            xr.x = 0u; xr.y = 0u;
            if (g0) xr = *reinterpret_cast<const uint2*>(xrow2 + 128 * it);
            U4 xu;
            xu.u.x = xr.x;
            xu.u.y = xr.y;
            xu.u.z = mask1;
            xu.u.w = 0u;
            f32x4 dP = __builtin_amdgcn_mfma_f32_16x16x32_bf16(wc0Af, xu.v, zc, 0, 0, 0);
            uint2 wv;
            wv.x = cvt_pk_bf16(fmaxf(dP[0], 0.f), fmaxf(dP[1], 0.f));
            wv.y = cvt_pk_bf16(fmaxf(dP[2], 0.f), fmaxf(dP[3], 0.f));
            *reinterpret_cast<uint2*>(c0w + it * 128) = wv;
        }
    }

    // preload phase-2 constants
    bf16x8 a1[8];
    #pragma unroll
    for (int c = 0; c < 8; ++c)
        a1[c] = reinterpret_cast<const bf16x8*>(wA1)[c * 64 + l];
    bf16x8 mfrag = reinterpret_cast<const bf16x8*>(Mp)[b * 64 + l];
    float cb1[4], bf2v[4];
    #pragma unroll
    for (int i = 0; i < 4; ++i) {
        int o = 4 * g + i;
        cb1[i] = (o < 8) ? b01[o] : b02[o - 8];
        float inv2 = g2[o] * rsqrtf(v2[o] + 1e-5f);
        bf2v[i] = bt2[o] - m2[o] * inv2;
    }

    __syncthreads();

    // ---- phase 2: fusion (dense slide) + c2-MFMA + store ----
    {
        const int gi0 = 8 * w;
        const unsigned short* frow = &f0T[16 * gi0 + lane15 + g + 2][0];
        const unsigned* c0r = &c0B[gi0 * 128 + lane15 * 8 + 4 * g];
        const size_t obase = (size_t)b * 16 * LL + p0 + 16 * gi0 + lane15;
        float* o0 = out + obase + (size_t)(4 * g + 0) * LL;
        float* o1 = out + obase + (size_t)(4 * g + 1) * LL;
        float* o2 = out + obase + (size_t)(4 * g + 2) * LL;
        float* o3 = out + obase + (size_t)(4 * g + 3) * LL;

        bf16x8 bb[8];
        #pragma unroll
        for (int c = 0; c < 8; ++c)
            bb[c] = *reinterpret_cast<const bf16x8*>(frow + 32 * c);
        #pragma unroll
        for (int it = 0; it < 8; ++it) {
            f32x4 dF = {cb1[0], cb1[1], cb1[2], cb1[3]};
            #pragma unroll
            for (int c = 0; c < 8; ++c)
                dF = __builtin_amdgcn_mfma_f32_16x16x32_bf16(a1[c], bb[c], dF, 0, 0, 0);

            U4 uu;
            uu.u = *reinterpret_cast<const uint4*>(c0r + it * 128);
            f32x4 dC = {bf2v[0], bf2v[1], bf2v[2], bf2v[3]};
            dC = __builtin_amdgcn_mfma_f32_16x16x32_bf16(mfrag, uu.v, dC, 0, 0, 0);

            float c20 = fmaxf(dC[0], 0.f), c21 = fmaxf(dC[1], 0.f);
            float c22 = fmaxf(dC[2], 0.f), c23 = fmaxf(dC[3], 0.f);
            float r0 = dF[0] + c20, r1 = dF[1] + c21;
            float r2 = dF[2] + c22, r3 = dF[3] + c23;
            if (!intr) {
                int p = p0 + 16 * (gi0 + it) + lane15;
                if (((p < 1) | (p > LL - 3)) && g >= 2) {
                    r0 = c20; r1 = c21; r2 = c22; r3 = c23;
                }
            }
            o0[16 * it] = r0;
            o1[16 * it] = r1;
            o2[16 * it] = r2;
            o3[16 * it] = r3;

            if (it < 7) {       // slide: chunks 4..7 -> 0..3, read 4 new
                bb[0] = bb[4]; bb[1] = bb[5]; bb[2] = bb[6]; bb[3] = bb[7];
                #pragma unroll
                for (int c = 4; c < 8; ++c)
                    bb[c] = *reinterpret_cast<const bf16x8*>(
                        frow + 16 * 8 * (it + 1) + 32 * c);
            }
        }
    }
}

extern "C" void kernel_launch(void* const* d_in, const int* in_sizes, int n_in,
                              void* d_out, int out_size, void* d_ws, size_t ws_size,
                              hipStream_t stream)
{
    const float* x    = (const float*)d_in[0];
    const float* w00  = (const float*)d_in[1];
    const float* b00  = (const float*)d_in[2];
    const float* w01  = (const float*)d_in[3];
    const float* b01  = (const float*)d_in[4];
    const float* w02  = (const float*)d_in[5];
    const float* b02  = (const float*)d_in[6];
    const float* wc1  = (const float*)d_in[7];
    const float* g1   = (const float*)d_in[8];
    const float* bt1  = (const float*)d_in[9];
    const float* m1   = (const float*)d_in[10];
    const float* v1   = (const float*)d_in[11];
    const float* beta = (const float*)d_in[12];
    const float* wc2  = (const float*)d_in[13];
    const float* g2   = (const float*)d_in[14];
    const float* bt2  = (const float*)d_in[15];
    const float* m2   = (const float*)d_in[16];
    const float* v2   = (const float*)d_in[17];

    char* wsb = (char*)d_ws;
    float* partialp       = (float*)wsb;                       // 2,097,152 B
    unsigned short* Mpp   = (unsigned short*)(wsb + 2097152);  // 262,144 B
    unsigned short* wA0p  = (unsigned short*)(wsb + 2359296);  // 6,144 B
    unsigned short* wA1p  = (unsigned short*)(wsb + 2365440);  // 8,192 B
    unsigned short* wc0Ap = (unsigned short*)(wsb + 2373632);  // 1,024 B
    float* o = (float*)d_out;

    hipLaunchKernelGGL(kernA1, dim3(2048), dim3(256), 0, stream,
        x, wc1, g1, bt1, m1, v1, partialp);
    hipLaunchKernelGGL(kernA2, dim3(256), dim3(256), 0, stream,
        partialp, beta, wc2, g2, bt2, m2, v2, w00, w01, w02,
        wc1, g1, bt1, m1, v1, Mpp, wA0p, wA1p, wc0Ap);
    hipLaunchKernelGGL(kernB, dim3(4096), dim3(256), 0, stream,
        x, b00, b01, b02, g2, bt2, m2, v2,
        wA0p, wA1p, wc0Ap, Mpp, o);
}

// Round 12
// 66.675 us; speedup vs baseline: 1.2690x; 1.0091x over previous
//
#include <hip/hip_runtime.h>

#define LL 8192

typedef __attribute__((ext_vector_type(8))) short bf16x8;
typedef __attribute__((ext_vector_type(4))) float f32x4;

union U4 { uint4 u; bf16x8 v; };

__device__ __forceinline__ float4 ld4(const float* p) {
    return *reinterpret_cast<const float4*>(p);
}
__device__ __forceinline__ unsigned short f2bf(float f) {
    union { float f; unsigned u; } v; v.f = f;
    unsigned r = v.u + 0x7fffu + ((v.u >> 16) & 1u);
    return (unsigned short)(r >> 16);
}
__device__ __forceinline__ unsigned cvt_pk_bf16(float lo, float hi) {
    unsigned r;
    asm("v_cvt_pk_bf16_f32 %0, %1, %2" : "=v"(r) : "v"(lo), "v"(hi));
    return r;
}

// ---------------------------------------------------------------------------
// kernA1: Gram of c0 over a 1024-position chunk via MFMA (A-frag == B-frag).
// grid = 256*8, block = 256
// ---------------------------------------------------------------------------
__global__ __launch_bounds__(256) void kernA1(
    const float* __restrict__ x, const float* __restrict__ wc1,
    const float* __restrict__ g1, const float* __restrict__ bt1,
    const float* __restrict__ m1, const float* __restrict__ v1,
    float* __restrict__ partial)
{
    __shared__ __align__(16) unsigned short c0f[16384];   // 32 KB frag-slot layout
    __shared__ float gsum[1024];                          // 4 KB

    const int blk = blockIdx.x;
    const int b = blk >> 3, chunk = blk & 7;
    const int t = threadIdx.x;
    const int w = t >> 6, l = t & 63;
    const float* xb = x + (size_t)b * 4 * LL;
    const int p0 = chunk << 10;

    const float4 x0 = ld4(&xb[0 * LL + p0 + 4 * t]);
    const float4 x1 = ld4(&xb[1 * LL + p0 + 4 * t]);
    const float4 x2 = ld4(&xb[2 * LL + p0 + 4 * t]);
    const float4 x3 = ld4(&xb[3 * LL + p0 + 4 * t]);

    const int p = 4 * t;
    unsigned short* dst =
        &c0f[(((p >> 5) << 6) + (((p >> 3) & 3) << 4)) * 8 + (p & 7)];
    #pragma unroll
    for (int u = 0; u < 16; ++u) {
        float inv = g1[u] * rsqrtf(v1[u] + 1e-5f);
        float w0 = wc1[u * 4 + 0] * inv, w1 = wc1[u * 4 + 1] * inv;
        float w2 = wc1[u * 4 + 2] * inv, w3 = wc1[u * 4 + 3] * inv;
        float bu = bt1[u] - m1[u] * inv;
        float ca = fmaxf(bu + w0 * x0.x + w1 * x1.x + w2 * x2.x + w3 * x3.x, 0.f);
        float cb = fmaxf(bu + w0 * x0.y + w1 * x1.y + w2 * x2.y + w3 * x3.y, 0.f);
        float cc = fmaxf(bu + w0 * x0.z + w1 * x1.z + w2 * x2.z + w3 * x3.z, 0.f);
        float cd = fmaxf(bu + w0 * x0.w + w1 * x1.w + w2 * x2.w + w3 * x3.w, 0.f);
        uint2 pk;
        pk.x = cvt_pk_bf16(ca, cb);
        pk.y = cvt_pk_bf16(cc, cd);
        *reinterpret_cast<uint2*>(dst + u * 8) = pk;
    }
    __syncthreads();

    f32x4 acc = {0.f, 0.f, 0.f, 0.f};
    #pragma unroll
    for (int m = 0; m < 8; ++m) {
        int slot = (w * 8 + m) * 64 + l;
        bf16x8 fr = *reinterpret_cast<const bf16x8*>(&c0f[slot * 8]);
        acc = __builtin_amdgcn_mfma_f32_16x16x32_bf16(fr, fr, acc, 0, 0, 0);
    }

    {
        int col = l & 15, rg = l >> 4;
        #pragma unroll
        for (int i = 0; i < 4; ++i)
            gsum[w * 256 + (rg * 4 + i) * 16 + col] = acc[i];
    }
    __syncthreads();
    partial[(size_t)(b * 8 + chunk) * 256 + t] =
        gsum[t] + gsum[256 + t] + gsum[512 + t] + gsum[768 + t];
}

// ---------------------------------------------------------------------------
// kernA2: reduce partials -> softmax -> M -> Mp; block 0 also packs weights.
// grid 256
// ---------------------------------------------------------------------------
__global__ __launch_bounds__(256) void kernA2(
    const float* __restrict__ partial, const float* __restrict__ beta_cam,
    const float* __restrict__ wc2, const float* __restrict__ g2,
    const float* __restrict__ bt2, const float* __restrict__ m2,
    const float* __restrict__ v2,
    const float* __restrict__ w00, const float* __restrict__ w01,
    const float* __restrict__ w02,
    const float* __restrict__ wc1, const float* __restrict__ g1,
    const float* __restrict__ bt1, const float* __restrict__ m1,
    const float* __restrict__ v1,
    unsigned short* __restrict__ Mp,
    unsigned short* __restrict__ wA0, unsigned short* __restrict__ wA1,
    unsigned short* __restrict__ wc0A)
{
    __shared__ float gram[16][16];
    __shared__ float attn[16][16];
    __shared__ float Msh[16][16];
    const int b = blockIdx.x, t = threadIdx.x;

    if (b == 0) {   // pack conv weights into MFMA fragment order
        for (int i = t; i < 384; i += 256) {
            const int c = i >> 6, li = i & 63;
            const int row = li & 15, g = li >> 4;
            #pragma unroll
            for (int j = 0; j < 8; ++j) {
                int ch = j & 3;
                int T = 8 * c + g + ((j >= 4) ? 4 : 0);
                float v = 0.f;
                if (row < 8) {
                    if (T < 32) v = w00[(row * 4 + ch) * 32 + T];
                } else {
                    int tt = T - 16;
                    if (tt >= 0) v = w00[((row - 8) * 4 + ch) * 32 + tt];
                }
                wA0[(c * 64 + li) * 8 + j] = f2bf(v);
            }
        }
        for (int i = t; i < 512; i += 256) {
            const int c = i >> 6, li = i & 63;
            const int row = li & 15, g = li >> 4;
            int q = 4 * c + g;
            #pragma unroll
            for (int j = 0; j < 8; ++j) {
                float v = 0.f;
                if (row < 8) {
                    if (q >= 7 && q <= 22) v = w01[(row * 8 + j) * 16 + (q - 7)];
                } else {
                    if (!(q & 1)) v = w02[((row - 8) * 8 + j) * 16 + (q >> 1)];
                }
                wA1[(c * 64 + li) * 8 + j] = f2bf(v);
            }
        }
        if (t < 64) {
            int u = t & 15, gg = t >> 4;
            float inv = g1[u] * rsqrtf(v1[u] + 1e-5f);
            #pragma unroll
            for (int j = 0; j < 8; ++j) {
                float v = 0.f;
                if (gg == 0) {
                    if (j < 4) v = wc1[u * 4 + j] * inv;
                    else if (j == 4) v = bt1[u] - m1[u] * inv;
                }
                wc0A[t * 8 + j] = f2bf(v);
            }
        }
    }

    const float* P = partial + (size_t)b * 2048;
    float s = 0.f;
    #pragma unroll
    for (int k = 0; k < 8; ++k) s += P[k * 256 + t];
    gram[t >> 4][t & 15] = s;
    __syncthreads();
    {
        const float beta = beta_cam[0];
        int d = t & 15;
        float gv = gram[t >> 4][d];
        float rm = gv;
        #pragma unroll
        for (int m = 1; m < 16; m <<= 1) rm = fmaxf(rm, __shfl_xor(rm, m, 64));
        float a = rm - gv;
        float am = a;
        #pragma unroll
        for (int m = 1; m < 16; m <<= 1) am = fmaxf(am, __shfl_xor(am, m, 64));
        float e = __expf(a - am);
        float ssum = e;
        #pragma unroll
        for (int m = 1; m < 16; m <<= 1) ssum += __shfl_xor(ssum, m, 64);
        attn[t >> 4][d] = beta * e / ssum;
    }
    __syncthreads();
    {
        int o = t >> 4, u = t & 15;
        float inv2 = g2[o] * rsqrtf(v2[o] + 1e-5f);
        float sm = wc2[o * 16 + u];
        #pragma unroll
        for (int d = 0; d < 16; ++d) sm += wc2[o * 16 + d] * attn[d][u];
        Msh[o][u] = sm * inv2;
    }
    __syncthreads();
    for (int idx = t; idx < 512; idx += 256) {
        int li = idx >> 3, j = idx & 7;
        int k = 8 * (li >> 4) + j, o = li & 15;
        float v = (k < 16) ? Msh[o][k] : 0.f;
        Mp[(size_t)b * 512 + idx] = f2bf(v);
    }
}

// ---------------------------------------------------------------------------
// kernB: MFMA conv pipeline; split MFMA accumulator chains (3+3 / 4+4) for
// ILP; c0 B-frags precomputed in phase 1 (per-wave, pre-redistributed).
// grid 256*16, block 256 (4 waves), T=512 positions per block.
// ---------------------------------------------------------------------------
__global__ __launch_bounds__(256, 4) void kernB(
    const float* __restrict__ x,
    const float* __restrict__ b00, const float* __restrict__ b01,
    const float* __restrict__ b02,
    const float* __restrict__ g2, const float* __restrict__ bt2,
    const float* __restrict__ m2, const float* __restrict__ v2,
    const unsigned short* __restrict__ wA0, const unsigned short* __restrict__ wA1,
    const unsigned short* __restrict__ wc0A,
    const unsigned short* __restrict__ Mp, float* __restrict__ out)
{
    // xT row i: elems 0..3 = x[0..3][p0-32+i], elems 4..7 = x[0..3][p0-32+i+4]
    __shared__ __align__(16) unsigned short xT[608][8];
    __shared__ __align__(16) unsigned short f0T[576][8];  // slot s <-> j = p0-16+s
    __shared__ __align__(16) unsigned c0B[4096];          // [32 grp][16 pos][8 upair]

    const int blk = blockIdx.x;
    const int b  = blk >> 4;
    const int p0 = (blk & 15) << 9;
    const int t  = threadIdx.x;
    const int w  = t >> 6, l = t & 63;
    const int lane15 = l & 15, g = l >> 4;
    const float* xb = x + (size_t)b * 4 * LL;
    const bool intr = (p0 != 0) && (p0 != 15 * 512);

    // ---- stage xT: one load per row -> row i lower + row i-4 upper ----
    if (intr) {
        for (int i = t; i < 608; i += 256) {
            int xp = p0 - 32 + i;
            float v0  = xb[0 * LL + xp];
            float v1_ = xb[1 * LL + xp];
            float v2_ = xb[2 * LL + xp];
            float v3_ = xb[3 * LL + xp];
            uint2 r;
            r.x = cvt_pk_bf16(v0, v1_);
            r.y = cvt_pk_bf16(v2_, v3_);
            *reinterpret_cast<uint2*>(&xT[i][0]) = r;
            if (i >= 4)
                *reinterpret_cast<uint2*>(&xT[i - 4][4]) = r;
        }
    } else {
        for (int i = t; i < 608; i += 256) {
            int xp = p0 - 32 + i;
            bool ok = (unsigned)xp < 8192u;
            float v0  = ok ? xb[0 * LL + xp] : 0.f;
            float v1_ = ok ? xb[1 * LL + xp] : 0.f;
            float v2_ = ok ? xb[2 * LL + xp] : 0.f;
            float v3_ = ok ? xb[3 * LL + xp] : 0.f;
            uint2 r;
            r.x = cvt_pk_bf16(v0, v1_);
            r.y = cvt_pk_bf16(v2_, v3_);
            *reinterpret_cast<uint2*>(&xT[i][0]) = r;
            if (i >= 4)
                *reinterpret_cast<uint2*>(&xT[i - 4][4]) = r;
        }
    }

    // preload phase-1 weights + bias + c0 A-frag
    bf16x8 a0[6];
    #pragma unroll
    for (int c = 0; c < 6; ++c)
        a0[c] = reinterpret_cast<const bf16x8*>(wA0)[c * 64 + l];
    float b00c[4];
    #pragma unroll
    for (int i = 0; i < 4; ++i) b00c[i] = b00[(4 * g + i) & 7];
    bf16x8 wc0Af = reinterpret_cast<const bf16x8*>(wc0A)[l];
    const unsigned mask1 = (g == 0) ? 0x3f80u : 0u;
    const bool g0 = (g == 0);
    const f32x4 zc = {0.f, 0.f, 0.f, 0.f};

    __syncthreads();

    // ---- phase 1a: fea0 via dual-packed MFMA, split 3+3 chains ----
    {
        const int ngrp = (w < 2) ? 5 : 4;
        const int grp0 = (w < 2) ? 5 * w : 10 + 4 * (w - 2);
        const unsigned short* xrow = &xT[32 * grp0 + lane15 + g][0];
        const int s_base = 32 * grp0 + lane15 + ((g >= 2) ? 16 : 0);
        unsigned short* wp = &f0T[s_base][4 * (g & 1)];
        bf16x8 bb[6];
        #pragma unroll
        for (int c = 0; c < 6; ++c)
            bb[c] = *reinterpret_cast<const bf16x8*>(xrow + 64 * c);
        #pragma unroll
        for (int it = 0; it < 5; ++it) {
            if (it < ngrp) {
                f32x4 da = {b00c[0], b00c[1], b00c[2], b00c[3]};
                f32x4 db = {0.f, 0.f, 0.f, 0.f};
                #pragma unroll
                for (int c = 0; c < 3; ++c)
                    da = __builtin_amdgcn_mfma_f32_16x16x32_bf16(a0[c], bb[c], da, 0, 0, 0);
                #pragma unroll
                for (int c = 3; c < 6; ++c)
                    db = __builtin_amdgcn_mfma_f32_16x16x32_bf16(a0[c], bb[c], db, 0, 0, 0);
                float e0 = da[0] + db[0], e1 = da[1] + db[1];
                float e2 = da[2] + db[2], e3 = da[3] + db[3];
                if (!intr) {
                    int j = p0 - 16 + s_base + 32 * it;
                    bool ok = (unsigned)j <= 8192u;
                    e0 = ok ? e0 : 0.f;  e1 = ok ? e1 : 0.f;
                    e2 = ok ? e2 : 0.f;  e3 = ok ? e3 : 0.f;
                }
                uint2 wv;
                wv.x = cvt_pk_bf16(e0, e1);
                wv.y = cvt_pk_bf16(e2, e3);
                *reinterpret_cast<uint2*>(wp + 256 * it) = wv;
                if (it + 1 < ngrp) {       // slide window: chunks 4,5 -> 0,1
                    bb[0] = bb[4]; bb[1] = bb[5];
                    #pragma unroll
                    for (int c = 2; c < 6; ++c)
                        bb[c] = *reinterpret_cast<const bf16x8*>(
                            xrow + 32 * 8 * (it + 1) + 64 * c);
                }
            }
        }
    }

    // ---- phase 1b: c0 B-frags for this wave's phase-2 groups (8w..8w+7) ----
    {
        const unsigned short* xrow2 = &xT[16 * (8 * w) + lane15 + 32][0];
        unsigned* c0w = &c0B[(8 * w) * 128 + lane15 * 8 + 2 * g];
        #pragma unroll
        for (int it = 0; it < 8; ++it) {
            uint2 xr;
            xr.x = 0u; xr.y = 0u;
            if (g0) xr = *reinterpret_cast<const uint2*>(xrow2 + 128 * it);
            U4 xu;
            xu.u.x = xr.x;
            xu.u.y = xr.y;
            xu.u.z = mask1;
            xu.u.w = 0u;
            f32x4 dP = __builtin_amdgcn_mfma_f32_16x16x32_bf16(wc0Af, xu.v, zc, 0, 0, 0);
            uint2 wv;
            wv.x = cvt_pk_bf16(fmaxf(dP[0], 0.f), fmaxf(dP[1], 0.f));
            wv.y = cvt_pk_bf16(fmaxf(dP[2], 0.f), fmaxf(dP[3], 0.f));
            *reinterpret_cast<uint2*>(c0w + it * 128) = wv;
        }
    }

    // preload phase-2 constants
    bf16x8 a1[8];
    #pragma unroll
    for (int c = 0; c < 8; ++c)
        a1[c] = reinterpret_cast<const bf16x8*>(wA1)[c * 64 + l];
    bf16x8 mfrag = reinterpret_cast<const bf16x8*>(Mp)[b * 64 + l];
    float cb1[4], bf2v[4];
    #pragma unroll
    for (int i = 0; i < 4; ++i) {
        int o = 4 * g + i;
        cb1[i] = (o < 8) ? b01[o] : b02[o - 8];
        float inv2 = g2[o] * rsqrtf(v2[o] + 1e-5f);
        bf2v[i] = bt2[o] - m2[o] * inv2;
    }

    __syncthreads();

    // ---- phase 2: fusion (split 4+4 chains) + c2-MFMA + store ----
    {
        const int gi0 = 8 * w;
        const unsigned short* frow = &f0T[16 * gi0 + lane15 + g + 2][0];
        const unsigned* c0r = &c0B[gi0 * 128 + lane15 * 8 + 4 * g];
        const size_t obase = (size_t)b * 16 * LL + p0 + 16 * gi0 + lane15;
        float* o0 = out + obase + (size_t)(4 * g + 0) * LL;
        float* o1 = out + obase + (size_t)(4 * g + 1) * LL;
        float* o2 = out + obase + (size_t)(4 * g + 2) * LL;
        float* o3 = out + obase + (size_t)(4 * g + 3) * LL;

        bf16x8 bb[8];
        #pragma unroll
        for (int c = 0; c < 8; ++c)
            bb[c] = *reinterpret_cast<const bf16x8*>(frow + 32 * c);
        #pragma unroll
        for (int it = 0; it < 8; ++it) {
            f32x4 dFa = {cb1[0], cb1[1], cb1[2], cb1[3]};
            f32x4 dFb = {0.f, 0.f, 0.f, 0.f};
            #pragma unroll
            for (int c = 0; c < 4; ++c)
                dFa = __builtin_amdgcn_mfma_f32_16x16x32_bf16(a1[c], bb[c], dFa, 0, 0, 0);
            #pragma unroll
            for (int c = 4; c < 8; ++c)
                dFb = __builtin_amdgcn_mfma_f32_16x16x32_bf16(a1[c], bb[c], dFb, 0, 0, 0);

            U4 uu;
            uu.u = *reinterpret_cast<const uint4*>(c0r + it * 128);
            f32x4 dC = {bf2v[0], bf2v[1], bf2v[2], bf2v[3]};
            dC = __builtin_amdgcn_mfma_f32_16x16x32_bf16(mfrag, uu.v, dC, 0, 0, 0);

            float c20 = fmaxf(dC[0], 0.f), c21 = fmaxf(dC[1], 0.f);
            float c22 = fmaxf(dC[2], 0.f), c23 = fmaxf(dC[3], 0.f);
            float r0 = dFa[0] + dFb[0] + c20, r1 = dFa[1] + dFb[1] + c21;
            float r2 = dFa[2] + dFb[2] + c22, r3 = dFa[3] + dFb[3] + c23;
            if (!intr) {
                int p = p0 + 16 * (gi0 + it) + lane15;
                if (((p < 1) | (p > LL - 3)) && g >= 2) {
                    r0 = c20; r1 = c21; r2 = c22; r3 = c23;
                }
            }
            o0[16 * it] = r0;
            o1[16 * it] = r1;
            o2[16 * it] = r2;
            o3[16 * it] = r3;

            if (it < 7) {       // slide: chunks 4..7 -> 0..3, read 4 new
                bb[0] = bb[4]; bb[1] = bb[5]; bb[2] = bb[6]; bb[3] = bb[7];
                #pragma unroll
                for (int c = 4; c < 8; ++c)
                    bb[c] = *reinterpret_cast<const bf16x8*>(
                        frow + 16 * 8 * (it + 1) + 32 * c);
            }
        }
    }
}

extern "C" void kernel_launch(void* const* d_in, const int* in_sizes, int n_in,
                              void* d_out, int out_size, void* d_ws, size_t ws_size,
                              hipStream_t stream)
{
    const float* x    = (const float*)d_in[0];
    const float* w00  = (const float*)d_in[1];
    const float* b00  = (const float*)d_in[2];
    const float* w01  = (const float*)d_in[3];
    const float* b01  = (const float*)d_in[4];
    const float* w02  = (const float*)d_in[5];
    const float* b02  = (const float*)d_in[6];
    const float* wc1  = (const float*)d_in[7];
    const float* g1   = (const float*)d_in[8];
    const float* bt1  = (const float*)d_in[9];
    const float* m1   = (const float*)d_in[10];
    const float* v1   = (const float*)d_in[11];
    const float* beta = (const float*)d_in[12];
    const float* wc2  = (const float*)d_in[13];
    const float* g2   = (const float*)d_in[14];
    const float* bt2  = (const float*)d_in[15];
    const float* m2   = (const float*)d_in[16];
    const float* v2   = (const float*)d_in[17];

    char* wsb = (char*)d_ws;
    float* partialp       = (float*)wsb;                       // 2,097,152 B
    unsigned short* Mpp   = (unsigned short*)(wsb + 2097152);  // 262,144 B
    unsigned short* wA0p  = (unsigned short*)(wsb + 2359296);  // 6,144 B
    unsigned short* wA1p  = (unsigned short*)(wsb + 2365440);  // 8,192 B
    unsigned short* wc0Ap = (unsigned short*)(wsb + 2373632);  // 1,024 B
    float* o = (float*)d_out;

    hipLaunchKernelGGL(kernA1, dim3(2048), dim3(256), 0, stream,
        x, wc1, g1, bt1, m1, v1, partialp);
    hipLaunchKernelGGL(kernA2, dim3(256), dim3(256), 0, stream,
        partialp, beta, wc2, g2, bt2, m2, v2, w00, w01, w02,
        wc1, g1, bt1, m1, v1, Mpp, wA0p, wA1p, wc0Ap);
    hipLaunchKernelGGL(kernB, dim3(4096), dim3(256), 0, stream,
        x, b00, b01, b02, g2, bt2, m2, v2,
        wA0p, wA1p, wc0Ap, Mpp, o);
}